// Round 2
// baseline (253.352 us; speedup 1.0000x reference)
//
#include <hip/hip_runtime.h>
#include <hip/hip_bf16.h>
#include <hip/hip_cooperative_groups.h>
#include <math.h>

#define F_N 5
#define K_N 6
#define T_N 12
#define M_N 3600
#define S_N 400
#define R_N 16
#define B_N 128

#define PI_F 3.14159265358979f
#define CLIP_HI 0.3490658503988659f
#define NEG_TWO_PI_OVER_C (-6.283185307179586f / 3.0e8f)
#define INV_TWO_PI 0.15915494309189535f

#define SA_BASE   0         // s_A  [11520][400] float32
#define MIC_BASE  4608000   // s_mic [11520][128] float32

#define NK 120              // K-chunks of 32 (120*32 = 3840 >= 3600), 8-divisible
#define KP (NK * 32)
#define SPK 8               // split-K partials
#define KCNT (NK / SPK)     // 15 chunks per partial — uniform (barrier-safe pairing)
#define W_ELEMS  (5 * 48 * KP)           // 921,600 bf16  W2[f][kk][48][32]
#define C_ELEMS  (SPK * 5 * 48 * 800)    // 1,536,000 f32
#define WS_NEED  ((size_t)W_ELEMS * 2 + (size_t)C_ELEMS * 4)   // ~8.0 MB

#define GRID_BLOCKS 500
#define SA_WORKS 750
#define EPI_WORKS 1230      // 750 SA + 480 mic

typedef __attribute__((ext_vector_type(8))) short bf16x8;
typedef __attribute__((ext_vector_type(4))) short s16x4;
typedef __attribute__((ext_vector_type(4))) float f32x4;

// Hardware sin/cos (v_sin_f32/v_cos_f32 take REVOLUTIONS; fract first).
__device__ __forceinline__ void fast_sincos(float x, float* s, float* c) {
    float r = x * INV_TWO_PI;
    r -= floorf(r);
    *s = __builtin_amdgcn_sinf(r);
    *c = __builtin_amdgcn_cosf(r);
}

// float -> bf16 bits, round-to-nearest-even
__device__ __forceinline__ ushort f2bf(float x) {
    unsigned u = __float_as_uint(x);
    unsigned r = u + 0x7fffu + ((u >> 16) & 1u);
    return (ushort)(r >> 16);
}

// =================== shared work routines (coop + fallback) ===================

// ---- phase A: W-pack. blk in [0,75), one m per thread (m = mblk*256+tid < 3840)
__device__ __forceinline__ void do_wpack(int blk, int tid,
    const float* __restrict__ w, const float* __restrict__ meta_theta,
    const float* __restrict__ fin, const float* __restrict__ txp,
    const float* __restrict__ rxp, const float* __restrict__ metap,
    ushort* __restrict__ Wbf, char* smem)
{
    float* pri = (float*)smem;                 // 144 f
    float* txs = pri + 2 * K_N * T_N;          // 36 f
    float* rxs = txs + T_N * 3;                // 48 f
    const int f = blk / 15;
    const int mblk = blk % 15;

    if (tid < K_N * T_N) {
        float sv, cv; fast_sincos(w[f * (K_N * T_N) + tid], &sv, &cv);
        pri[tid * 2] = cv; pri[tid * 2 + 1] = sv;
    }
    if (tid >= 64 && tid < 64 + T_N * 3) txs[tid - 64] = txp[tid - 64];
    if (tid >= 128 && tid < 128 + R_N * 3) rxs[tid - 128] = rxp[tid - 128];
    __syncthreads();

    const int m = mblk * 256 + tid;            // < KP always
    ushort* wb = Wbf + ((size_t)(f * NK + (m >> 5)) * 48) * 32 + (m & 31);

    if (m >= M_N) {                            // K padding columns (exact zeros)
        for (int row = 0; row < 48; ++row) wb[row * 32] = 0;
        return;                                // no barriers below — safe
    }

    const float px = metap[m * 3 + 0];
    const float py = metap[m * 3 + 1];
    const float pz = metap[m * 3 + 2];
    const float coef = NEG_TWO_PI_OVER_C * fin[f];

    float th = meta_theta[m];
    th = fminf(fmaxf(th, -PI_F), CLIP_HI);
    float phs, phc; fast_sincos(th, &phs, &phc);

    float hre[T_N], him[T_N];
#pragma unroll
    for (int t = 0; t < T_N; ++t) {
        float dx = txs[t * 3 + 0] - px, dy = txs[t * 3 + 1] - py, dz = txs[t * 3 + 2] - pz;
        float d = sqrtf(dx * dx + dy * dy + dz * dz);
        float amp = 1e-3f / (d * d);
        float sv, cv; fast_sincos(coef * d, &sv, &cv);
        hre[t] = amp * cv; him[t] = amp * sv;
    }
#pragma unroll
    for (int k = 0; k < K_N; ++k) {
        float ar = 0.f, ai = 0.f;
#pragma unroll
        for (int t = 0; t < T_N; ++t) {
            float pr = pri[(k * T_N + t) * 2], pim = pri[(k * T_N + t) * 2 + 1];
            ar += pr * hre[t] - pim * him[t];
            ai += pr * him[t] + pim * hre[t];
        }
        wb[k * 32]        = f2bf(ar * phc - ai * phs);
        wb[(22 + k) * 32] = f2bf(ar * phs + ai * phc);
    }
#pragma unroll
    for (int r = 0; r < R_N; ++r) {
        float dx = rxs[r * 3 + 0] - px, dy = rxs[r * 3 + 1] - py, dz = rxs[r * 3 + 2] - pz;
        float d = sqrtf(dx * dx + dy * dy + dz * dz);
        float amp = 1e-3f / (d * d);
        float sv, cv; fast_sincos(coef * d, &sv, &cv);
        float cr = amp * cv, ci = amp * sv;
        wb[(6 + r) * 32]  = f2bf(cr * phc - ci * phs);
        wb[(28 + r) * 32] = f2bf(cr * phs + ci * phc);
    }
#pragma unroll
    for (int row = 44; row < 48; ++row) wb[row * 32] = 0;
}

// ---- phase B: one GEMM work (f,nblk,ksp), 128 threads (2 waves), B gen in LDS.
// tilebase: 2 dbuf x [32 cols][40 kpad] ushort = 5120 B. __syncthreads may span
// more threads than this half — iteration count is uniform (KCNT), so safe.
__device__ __forceinline__ void do_gemm_half(int wk, int t128,
    const float* __restrict__ fin, const float* __restrict__ metap,
    const float* __restrict__ scenep, const ushort* __restrict__ Wbf,
    float* __restrict__ Cp, char* tilebase)
{
    const int f = wk / 200;
    const int rem = wk % 200;
    const int nblk = rem / SPK;
    const int ksp = rem % SPK;
    const int wave = t128 >> 6;
    const int lane = t128 & 63;
    const int quad = lane >> 4;
    const int l16 = lane & 15;
    const int kbeg = ksp * KCNT;

    ushort (*tile)[32][40] = (ushort (*)[32][40])tilebase;

    // producer role: thread (p, kq) computes k = kq*4..+3 for scene slot p
    const int p  = t128 & 15;
    const int kq = t128 >> 4;                    // 0..7
    const int s  = nblk * 16 + p;                // < 400
    const float coef = NEG_TWO_PI_OVER_C * fin[f];
    const float sx = scenep[s * 3 + 0];
    const float sy = scenep[s * 3 + 1];
    const float sz = scenep[s * 3 + 2];

    const int n = nblk * 32 + wave * 16 + l16;   // < 800, col = 2s(+1)

    f32x4 acc0 = {0.f, 0.f, 0.f, 0.f};
    f32x4 acc1 = {0.f, 0.f, 0.f, 0.f};
    f32x4 acc2 = {0.f, 0.f, 0.f, 0.f};

    auto produce = [&](int buf, int kb) {
        const int k0 = kq * 4;
        const int mb = kb * 32 + k0;
        s16x4 r4, i4;
#pragma unroll
        for (int j = 0; j < 4; ++j) {
            const int m = mb + j;
            float re = 0.f, im = 0.f;
            if (m < M_N) {
                float px = metap[m * 3 + 0], py = metap[m * 3 + 1], pz = metap[m * 3 + 2];
                float dx = px - sx, dy = py - sy, dz = pz - sz;
                float d = sqrtf(dx * dx + dy * dy + dz * dz);
                float amp = 1e-3f / (d * d);
                float sv, cv; fast_sincos(coef * d, &sv, &cv);
                re = amp * cv; im = amp * sv;
            }
            r4[j] = (short)f2bf(re);
            i4[j] = (short)f2bf(im);
        }
        *(s16x4*)&tile[buf][2 * p][k0]     = r4;   // Re -> col 2s
        *(s16x4*)&tile[buf][2 * p + 1][k0] = i4;   // Im -> col 2s+1
    };

    produce(0, kbeg);
    __syncthreads();

    for (int kk = 0; kk < KCNT; ++kk) {
        const int kb = kbeg + kk;
        const int cur = kk & 1;
        if (kk + 1 < KCNT) produce(cur ^ 1, kb + 1);   // parallel sincos, other buf

        bf16x8 b = *(const bf16x8*)&tile[cur][wave * 16 + l16][quad * 8];
        const ushort* wbase = Wbf + ((size_t)(f * NK + kb) * 48) * 32 + quad * 8;
        bf16x8 a0 = *(const bf16x8*)(wbase + (size_t)l16 * 32);
        bf16x8 a1 = *(const bf16x8*)(wbase + (size_t)(16 + l16) * 32);
        bf16x8 a2 = *(const bf16x8*)(wbase + (size_t)(32 + l16) * 32);
        acc0 = __builtin_amdgcn_mfma_f32_16x16x32_bf16(a0, b, acc0, 0, 0, 0);
        acc1 = __builtin_amdgcn_mfma_f32_16x16x32_bf16(a1, b, acc1, 0, 0, 0);
        acc2 = __builtin_amdgcn_mfma_f32_16x16x32_bf16(a2, b, acc2, 0, 0, 0);
        __syncthreads();
    }

    // C/D layout: col = lane&15, row = quad*4 + reg
    float* cb = Cp + ((size_t)(ksp * 5 + f) * 48) * 800;
#pragma unroll
    for (int i = 0; i < 4; ++i) {
        int row = quad * 4 + i;
        cb[(size_t)row * 800 + n]        = acc0[i];
        cb[(size_t)(16 + row) * 800 + n] = acc1[i];
        cb[(size_t)(32 + row) * 800 + n] = acc2[i];
    }
}

// Combine split-K partials + complex reassembly (col 2s = Re, 2s+1 = Im).
__device__ __forceinline__ void combineC(const float* __restrict__ Cp, int f, int row,
                                         int s, float* re, float* im) {
    float r = 0.f, i = 0.f;
#pragma unroll
    for (int pp = 0; pp < SPK; ++pp) {
        const float* c = Cp + ((size_t)(pp * 5 + f) * 48) * 800;
        float arr = c[(size_t)row * 800 + 2 * s];
        float ari = c[(size_t)row * 800 + 2 * s + 1];
        float air = c[(size_t)(22 + row) * 800 + 2 * s];
        float aii = c[(size_t)(22 + row) * 800 + 2 * s + 1];
        r += arr - aii;
        i += ari + air;
    }
    *re = r; *im = i;
}

// ---- phase C: one epilogue work (w in [0,1230)), 256 threads.
__device__ __forceinline__ void do_epilogue(int w, int tid,
    const float* __restrict__ Cp, const float* __restrict__ T,
    float* __restrict__ out, char* smem)
{
    if (w < SA_WORKS) {
        int i = w * 256 + tid;             // 750*256 == 192000
        int s = i % S_N; int rest = i / S_N;
        int k = rest % K_N; rest /= K_N;
        int f = rest % F_N; int r = rest / F_N;

        float ar, ai, br, bi;
        combineC(Cp, f, k, s, &ar, &ai);
        combineC(Cp, f, 6 + r, s, &br, &bi);
        float cr = ar * br - ai * bi;
        float ci = ar * bi + ai * br;

        int base = (r * F_N + f) * 72;
#pragma unroll
        for (int j = 0; j < 12; ++j) {
            int row = base + j * K_N + k;
            out[SA_BASE + (size_t)row * S_N + s] = cr;
            out[SA_BASE + (size_t)(5760 + row) * S_N + s] = ci;
        }
    } else {
        int bk = w - SA_WORKS;             // 0..479
        int k = bk % K_N;
        int f = (bk / K_N) % F_N;
        int r = bk / (K_N * F_N);

        float* cre = (float*)smem;         // 400
        float* cim = cre + S_N;            // 400
        float* pR  = cim + S_N;            // 256
        float* pI  = pR + 256;             // 256  -> 5248 B total

        for (int s = tid; s < S_N; s += 256) {
            float ar, ai, br, bi;
            combineC(Cp, f, k, s, &ar, &ai);
            combineC(Cp, f, 6 + r, s, &br, &bi);
            cre[s] = ar * br - ai * bi;
            cim[s] = ar * bi + ai * br;
        }
        __syncthreads();

        const int b = tid & 127;
        const int hs = tid >> 7;
        float accR = 0.f, accI = 0.f;
        const int sBeg = hs * 200, sEnd = sBeg + 200;
#pragma unroll 4
        for (int s = sBeg; s < sEnd; ++s) {
            float tv = T[s * B_N + b];
            accR += cre[s] * tv;
            accI += cim[s] * tv;
        }
        pR[tid] = accR; pI[tid] = accI;
        __syncthreads();
        if (tid < 128) {
            accR = pR[tid] + pR[tid + 128];
            accI = pI[tid] + pI[tid + 128];
            int base = (r * F_N + f) * 72;
#pragma unroll
            for (int j = 0; j < 12; ++j) {
                int row = base + j * K_N + k;
                out[MIC_BASE + (size_t)row * B_N + b] = accR;
                out[MIC_BASE + (size_t)(5760 + row) * B_N + b] = accI;
            }
        }
    }
}

// =================== single cooperative kernel (3 phases) ===================
__global__ __launch_bounds__(256, 2) void fused_all_kernel(
    const float* __restrict__ w, const float* __restrict__ meta_theta,
    const float* __restrict__ fin, const float* __restrict__ txp,
    const float* __restrict__ rxp, const float* __restrict__ metap,
    const float* __restrict__ scenep, ushort* __restrict__ Wbf,
    float* __restrict__ Cp, const float* __restrict__ T,
    float* __restrict__ out)
{
    __shared__ __align__(16) char smem[10240];
    const int tid = threadIdx.x;
    const int blk = blockIdx.x;

    // phase A: W-pack (75 block-works)
    if (blk < 75)
        do_wpack(blk, tid, w, meta_theta, fin, txp, rxp, metap, Wbf, smem);
    cooperative_groups::this_grid().sync();

    // phase B: 1000 GEMM works, 2 per block (half = tid>>7), uniform KCNT
    {
        const int half = tid >> 7;
        do_gemm_half(blk * 2 + half, tid & 127, fin, metap, scenep, Wbf, Cp,
                     smem + half * 5120);
    }
    cooperative_groups::this_grid().sync();

    // phase C: 1230 epilogue works over 500 blocks
    for (int wv = blk; wv < EPI_WORKS; wv += GRID_BLOCKS) {
        __syncthreads();                   // smem handoff between works/phases
        do_epilogue(wv, tid, Cp, T, out, smem);
    }
}

// =================== non-coop fallback (3 dispatches) ===================
__global__ __launch_bounds__(256) void stage_kernel(
    const float* __restrict__ w, const float* __restrict__ meta_theta,
    const float* __restrict__ fin, const float* __restrict__ txp,
    const float* __restrict__ rxp, const float* __restrict__ metap,
    ushort* __restrict__ Wbf)
{
    __shared__ __align__(16) char smem[1024];
    do_wpack(blockIdx.x, threadIdx.x, w, meta_theta, fin, txp, rxp, metap, Wbf, smem);
}

__global__ __launch_bounds__(128) void gemm_fused_kernel(
    const ushort* __restrict__ Wbf, const float* __restrict__ fin,
    const float* __restrict__ metap, const float* __restrict__ scenep,
    float* __restrict__ Cp)
{
    __shared__ __align__(16) char tile[5120];
    do_gemm_half(blockIdx.x, threadIdx.x, fin, metap, scenep, Wbf, Cp, tile);
}

__global__ __launch_bounds__(256) void epilogue2_kernel(
    const float* __restrict__ Cp, const float* __restrict__ T,
    float* __restrict__ out)
{
    __shared__ __align__(16) char smem[5248];
    do_epilogue(blockIdx.x, threadIdx.x, Cp, T, out, smem);
}

// ---------------- Fallback path (round-14, used if ws too small) ----------------
#define SA_BLOCKS 750
__global__ __launch_bounds__(256) void prep_kernel(
    const float* __restrict__ w, const float* __restrict__ meta_theta,
    const float* __restrict__ fin, const float* __restrict__ txp,
    const float* __restrict__ rxp, const float* __restrict__ metap,
    float* __restrict__ A1, float* __restrict__ H4p)
{
    __shared__ float pri[K_N * T_N * 2];
    __shared__ float txs[T_N * 3];
    __shared__ float rxs[R_N * 3];
    const int tid = threadIdx.x;
    const int f = blockIdx.x / 15;
    const int mblk = blockIdx.x % 15;

    if (tid < K_N * T_N) {
        float sv, cv; fast_sincos(w[f * (K_N * T_N) + tid], &sv, &cv);
        pri[tid * 2] = cv; pri[tid * 2 + 1] = sv;
    }
    if (tid >= 64 && tid < 64 + T_N * 3) txs[tid - 64] = txp[tid - 64];
    if (tid >= 128 && tid < 128 + R_N * 3) rxs[tid - 128] = rxp[tid - 128];
    __syncthreads();

    const int m = mblk * 256 + tid;
    if (m >= M_N) return;

    const float px = metap[m * 3 + 0];
    const float py = metap[m * 3 + 1];
    const float pz = metap[m * 3 + 2];
    const float coef = NEG_TWO_PI_OVER_C * fin[f];

    float th = meta_theta[m];
    th = fminf(fmaxf(th, -PI_F), CLIP_HI);
    float phs, phc; fast_sincos(th, &phs, &phc);

    float hre[T_N], him[T_N];
#pragma unroll
    for (int t = 0; t < T_N; ++t) {
        float dx = txs[t * 3 + 0] - px, dy = txs[t * 3 + 1] - py, dz = txs[t * 3 + 2] - pz;
        float d = sqrtf(dx * dx + dy * dy + dz * dz);
        float amp = 1e-3f / (d * d);
        float sv, cv; fast_sincos(coef * d, &sv, &cv);
        hre[t] = amp * cv; him[t] = amp * sv;
    }
    float* a1 = A1 + ((size_t)f * M_N + m) * (K_N * 2);
#pragma unroll
    for (int k = 0; k < K_N; ++k) {
        float ar = 0.f, ai = 0.f;
#pragma unroll
        for (int t = 0; t < T_N; ++t) {
            float pr = pri[(k * T_N + t) * 2], pim = pri[(k * T_N + t) * 2 + 1];
            ar += pr * hre[t] - pim * him[t];
            ai += pr * him[t] + pim * hre[t];
        }
        a1[k * 2]     = ar * phc - ai * phs;
        a1[k * 2 + 1] = ar * phs + ai * phc;
    }
    float* h4 = H4p + ((size_t)f * M_N + m) * (R_N * 2);
#pragma unroll
    for (int r = 0; r < R_N; ++r) {
        float dx = rxs[r * 3 + 0] - px, dy = rxs[r * 3 + 1] - py, dz = rxs[r * 3 + 2] - pz;
        float d = sqrtf(dx * dx + dy * dy + dz * dz);
        float amp = 1e-3f / (d * d);
        float sv, cv; fast_sincos(coef * d, &sv, &cv);
        float cr = amp * cv, ci = amp * sv;
        h4[r * 2]     = cr * phc - ci * phs;
        h4[r * 2 + 1] = cr * phs + ci * phc;
    }
}

__global__ __launch_bounds__(256, 2) void main_kernel(
    const float* __restrict__ fin, const float* __restrict__ metap,
    const float* __restrict__ scenep, const float* __restrict__ A1,
    const float* __restrict__ H4p, float* __restrict__ A2, float* __restrict__ Bm)
{
    const int f = blockIdx.x / 200;
    const int sq = blockIdx.x % 200;
    const int s0 = 2 * sq, s1 = s0 + 1;
    const int tid = threadIdx.x;

    const float coef = NEG_TWO_PI_OVER_C * fin[f];
    const float sx0 = scenep[s0 * 3], sy0 = scenep[s0 * 3 + 1], sz0 = scenep[s0 * 3 + 2];
    const float sx1 = scenep[s1 * 3], sy1 = scenep[s1 * 3 + 1], sz1 = scenep[s1 * 3 + 2];

    float acc[88];
#pragma unroll
    for (int i = 0; i < 88; ++i) acc[i] = 0.f;

    const float4* a1base = (const float4*)(A1 + (size_t)f * M_N * (K_N * 2));
    const float4* h4base = (const float4*)(H4p + (size_t)f * M_N * (R_N * 2));

    for (int m = tid; m < M_N; m += 256) {
        float px = metap[m * 3 + 0], py = metap[m * 3 + 1], pz = metap[m * 3 + 2];
        float dx0 = px - sx0, dy0 = py - sy0, dz0 = pz - sz0;
        float d0 = sqrtf(dx0 * dx0 + dy0 * dy0 + dz0 * dz0);
        float dx1 = px - sx1, dy1 = py - sy1, dz1 = pz - sz1;
        float d1 = sqrtf(dx1 * dx1 + dy1 * dy1 + dz1 * dz1);
        float sv0, cv0, sv1, cv1;
        fast_sincos(coef * d0, &sv0, &cv0);
        fast_sincos(coef * d1, &sv1, &cv1);
        float amp0 = 1e-3f / (d0 * d0), amp1 = 1e-3f / (d1 * d1);
        float h2r0 = amp0 * cv0, h2i0 = amp0 * sv0;
        float h2r1 = amp1 * cv1, h2i1 = amp1 * sv1;

        const float4* a1 = a1base + (size_t)m * 3;
#pragma unroll
        for (int q = 0; q < 3; ++q) {
            float4 v = a1[q];
            acc[4 * q + 0] += v.x * h2r0 - v.y * h2i0;
            acc[4 * q + 1] += v.x * h2i0 + v.y * h2r0;
            acc[4 * q + 2] += v.z * h2r0 - v.w * h2i0;
            acc[4 * q + 3] += v.z * h2i0 + v.w * h2r0;
            acc[44 + 4 * q + 0] += v.x * h2r1 - v.y * h2i1;
            acc[44 + 4 * q + 1] += v.x * h2i1 + v.y * h2r1;
            acc[44 + 4 * q + 2] += v.z * h2r1 - v.w * h2i1;
            acc[44 + 4 * q + 3] += v.z * h2i1 + v.w * h2r1;
        }
        const float4* h4 = h4base + (size_t)m * 8;
#pragma unroll
        for (int q = 0; q < 8; ++q) {
            float4 v = h4[q];
            acc[12 + 4 * q + 0] += v.x * h2r0 - v.y * h2i0;
            acc[12 + 4 * q + 1] += v.x * h2i0 + v.y * h2r0;
            acc[12 + 4 * q + 2] += v.z * h2r0 - v.w * h2i0;
            acc[12 + 4 * q + 3] += v.z * h2i0 + v.w * h2r0;
            acc[56 + 4 * q + 0] += v.x * h2r1 - v.y * h2i1;
            acc[56 + 4 * q + 1] += v.x * h2i1 + v.y * h2r1;
            acc[56 + 4 * q + 2] += v.z * h2r1 - v.w * h2i1;
            acc[56 + 4 * q + 3] += v.z * h2i1 + v.w * h2r1;
        }
    }

#pragma unroll
    for (int off = 32; off > 0; off >>= 1) {
#pragma unroll
        for (int i = 0; i < 88; ++i) acc[i] += __shfl_down(acc[i], off);
    }
    __shared__ float red[4][88];
    const int wave = tid >> 6, lane = tid & 63;
    if (lane == 0) {
#pragma unroll
        for (int i = 0; i < 88; ++i) red[wave][i] = acc[i];
    }
    __syncthreads();
    if (tid < 88) {
        float v = red[0][tid] + red[1][tid] + red[2][tid] + red[3][tid];
        int half = tid / 44, slot = tid - 44 * half;
        int s = half ? s1 : s0;
        if (slot < 12) {
            int k = slot >> 1, c = slot & 1;
            A2[(((size_t)f * K_N + k) * S_N + s) * 2 + c] = v;
        } else {
            int j = slot - 12; int r = j >> 1, c = j & 1;
            Bm[(((size_t)f * S_N + s) * R_N + r) * 2 + c] = v;
        }
    }
}

__global__ __launch_bounds__(256) void epilogue_kernel(
    const float* __restrict__ A2, const float* __restrict__ Bm,
    const float* __restrict__ T, float* __restrict__ out)
{
    __shared__ float cre[S_N], cim[S_N];
    __shared__ float pR[256], pI[256];
    const int tid = threadIdx.x;
    const int blk = blockIdx.x;

    if (blk < SA_BLOCKS) {
        int i = blk * 256 + tid;
        int s = i % S_N; int rest = i / S_N;
        int k = rest % K_N; rest /= K_N;
        int f = rest % F_N; int r = rest / F_N;

        float ar = A2[((f * K_N + k) * S_N + s) * 2];
        float ai = A2[((f * K_N + k) * S_N + s) * 2 + 1];
        float br = Bm[((f * S_N + s) * R_N + r) * 2];
        float bi = Bm[((f * S_N + s) * R_N + r) * 2 + 1];
        float cr = ar * br - ai * bi;
        float ci = ar * bi + ai * br;

        int base = (r * F_N + f) * 72;
#pragma unroll
        for (int j = 0; j < 12; ++j) {
            int row = base + j * K_N + k;
            out[SA_BASE + (size_t)row * S_N + s] = cr;
            out[SA_BASE + (size_t)(5760 + row) * S_N + s] = ci;
        }
    } else {
        int bk = blk - SA_BLOCKS;
        int k = bk % K_N;
        int f = (bk / K_N) % F_N;
        int r = bk / (K_N * F_N);

        for (int s = tid; s < S_N; s += 256) {
            float ar = A2[((f * K_N + k) * S_N + s) * 2];
            float ai = A2[((f * K_N + k) * S_N + s) * 2 + 1];
            float br = Bm[((f * S_N + s) * R_N + r) * 2];
            float bi = Bm[((f * S_N + s) * R_N + r) * 2 + 1];
            cre[s] = ar * br - ai * bi;
            cim[s] = ar * bi + ai * br;
        }
        __syncthreads();

        const int b = tid & 127;
        const int hs = tid >> 7;
        float accR = 0.f, accI = 0.f;
        const int sBeg = hs * 200, sEnd = sBeg + 200;
#pragma unroll 4
        for (int s = sBeg; s < sEnd; ++s) {
            float tv = T[s * B_N + b];
            accR += cre[s] * tv;
            accI += cim[s] * tv;
        }
        pR[tid] = accR; pI[tid] = accI;
        __syncthreads();
        if (tid < 128) {
            accR = pR[tid] + pR[tid + 128];
            accI = pI[tid] + pI[tid + 128];
            int base = (r * F_N + f) * 72;
#pragma unroll
            for (int j = 0; j < 12; ++j) {
                int row = base + j * K_N + k;
                out[MIC_BASE + (size_t)row * B_N + b] = accR;
                out[MIC_BASE + (size_t)(5760 + row) * B_N + b] = accI;
            }
        }
    }
}

extern "C" void kernel_launch(void* const* d_in, const int* in_sizes, int n_in,
                              void* d_out, int out_size, void* d_ws, size_t ws_size,
                              hipStream_t stream) {
    const float* T  = (const float*)d_in[0];
    const float* w  = (const float*)d_in[1];
    const float* th = (const float*)d_in[2];
    const float* fr = (const float*)d_in[3];
    const float* tx = (const float*)d_in[4];
    const float* rx = (const float*)d_in[5];
    const float* mp = (const float*)d_in[6];
    const float* sp = (const float*)d_in[7];

    float* out = (float*)d_out;

    if (ws_size >= WS_NEED) {
        ushort* Wbf = (ushort*)d_ws;
        float* Cp = (float*)((char*)d_ws + (size_t)W_ELEMS * 2);

        void* args[] = { (void*)&w, (void*)&th, (void*)&fr, (void*)&tx, (void*)&rx,
                         (void*)&mp, (void*)&sp, (void*)&Wbf, (void*)&Cp,
                         (void*)&T, (void*)&out };
        hipError_t e = hipLaunchCooperativeKernel(
            (const void*)fused_all_kernel, dim3(GRID_BLOCKS), dim3(256),
            args, 0u, stream);
        if (e != hipSuccess) {
            // non-coop fallback: 3 dispatches, same math
            stage_kernel<<<75, 256, 0, stream>>>(w, th, fr, tx, rx, mp, Wbf);
            gemm_fused_kernel<<<1000, 128, 0, stream>>>(Wbf, fr, mp, sp, Cp);
            epilogue2_kernel<<<EPI_WORKS, 256, 0, stream>>>(Cp, T, out);
        }
    } else {
        float* ws  = (float*)d_ws;
        float* A1  = ws;
        float* H4p = ws + 216000;
        float* A2  = ws + 792000;
        float* Bm  = ws + 816000;

        prep_kernel<<<75, 256, 0, stream>>>(w, th, fr, tx, rx, mp, A1, H4p);
        main_kernel<<<F_N * 200, 256, 0, stream>>>(fr, mp, sp, A1, H4p, A2, Bm);
        epilogue_kernel<<<SA_BLOCKS + 480, 256, 0, stream>>>(A2, Bm, T, out);
    }
}

// Round 3
// 121.309 us; speedup vs baseline: 2.0885x; 2.0885x over previous
//
#include <hip/hip_runtime.h>
#include <hip/hip_bf16.h>
#include <math.h>

#define F_N 5
#define K_N 6
#define T_N 12
#define M_N 3600
#define S_N 400
#define R_N 16
#define B_N 128

#define PI_F 3.14159265358979f
#define CLIP_HI 0.3490658503988659f
#define NEG_TWO_PI_OVER_C (-6.283185307179586f / 3.0e8f)
#define INV_TWO_PI 0.15915494309189535f

#define SA_BASE   0         // s_A  [11520][400] float32
#define MIC_BASE  4608000   // s_mic [11520][128] float32

#define NK 120              // K-chunks of 32 (120*32 = 3840 >= 3600), 8-divisible
#define KP (NK * 32)
#define SPK 8               // split-K blocks (partials merged via atomicAdd)
#define KCNT (NK / SPK)     // 15 chunks per partial — uniform
#define W_ELEMS  (5 * 48 * KP)           // 921,600 bf16  W2[f][kk][48][32]
#define C_ELEMS  (5 * 48 * 800)          // 192,000 f32 — single merged plane
#define WS_NEED  ((size_t)W_ELEMS * 2 + (size_t)C_ELEMS * 4)   // ~2.6 MB

#define STAGE_BLOCKS 105    // 75 W-pack + 30 Cp-zero
#define SA_WORKS 750
#define EPI_WORKS 1230      // 750 SA + 480 mic

typedef __attribute__((ext_vector_type(8))) short bf16x8;
typedef __attribute__((ext_vector_type(4))) short s16x4;
typedef __attribute__((ext_vector_type(4))) float f32x4;

// Hardware sin/cos (v_sin_f32/v_cos_f32 take REVOLUTIONS; fract first).
__device__ __forceinline__ void fast_sincos(float x, float* s, float* c) {
    float r = x * INV_TWO_PI;
    r -= floorf(r);
    *s = __builtin_amdgcn_sinf(r);
    *c = __builtin_amdgcn_cosf(r);
}

// float -> bf16 bits, round-to-nearest-even
__device__ __forceinline__ ushort f2bf(float x) {
    unsigned u = __float_as_uint(x);
    unsigned r = u + 0x7fffu + ((u >> 16) & 1u);
    return (ushort)(r >> 16);
}

// =================== stage: W-pack (75 blocks) + Cp zero (30 blocks) ==========
__global__ __launch_bounds__(256) void stage_kernel(
    const float* __restrict__ w, const float* __restrict__ meta_theta,
    const float* __restrict__ fin, const float* __restrict__ txp,
    const float* __restrict__ rxp, const float* __restrict__ metap,
    ushort* __restrict__ Wbf, float* __restrict__ Cp)
{
    const int tid = threadIdx.x;
    const int blk = blockIdx.x;

    if (blk >= 75) {                           // ---- Cp zero (0.77 MB) ----
        float4* cz = (float4*)Cp;              // 48000 float4
        const int t = (blk - 75) * 256 + tid;  // 7680 threads
        for (int i = t; i < C_ELEMS / 4; i += 30 * 256) {
            cz[i] = make_float4(0.f, 0.f, 0.f, 0.f);
        }
        return;
    }

    __shared__ float pri[K_N * T_N * 2];
    __shared__ float txs[T_N * 3];
    __shared__ float rxs[R_N * 3];
    const int f = blk / 15;
    const int mblk = blk % 15;

    if (tid < K_N * T_N) {
        float sv, cv; fast_sincos(w[f * (K_N * T_N) + tid], &sv, &cv);
        pri[tid * 2] = cv; pri[tid * 2 + 1] = sv;
    }
    if (tid >= 64 && tid < 64 + T_N * 3) txs[tid - 64] = txp[tid - 64];
    if (tid >= 128 && tid < 128 + R_N * 3) rxs[tid - 128] = rxp[tid - 128];
    __syncthreads();

    const int m = mblk * 256 + tid;            // < KP always
    ushort* wb = Wbf + ((size_t)(f * NK + (m >> 5)) * 48) * 32 + (m & 31);

    if (m >= M_N) {                            // K padding columns (exact zeros)
        for (int row = 0; row < 48; ++row) wb[row * 32] = 0;
        return;
    }

    const float px = metap[m * 3 + 0];
    const float py = metap[m * 3 + 1];
    const float pz = metap[m * 3 + 2];
    const float coef = NEG_TWO_PI_OVER_C * fin[f];

    float th = meta_theta[m];
    th = fminf(fmaxf(th, -PI_F), CLIP_HI);
    float phs, phc; fast_sincos(th, &phs, &phc);

    float hre[T_N], him[T_N];
#pragma unroll
    for (int t = 0; t < T_N; ++t) {
        float dx = txs[t * 3 + 0] - px, dy = txs[t * 3 + 1] - py, dz = txs[t * 3 + 2] - pz;
        float d = sqrtf(dx * dx + dy * dy + dz * dz);
        float amp = 1e-3f / (d * d);
        float sv, cv; fast_sincos(coef * d, &sv, &cv);
        hre[t] = amp * cv; him[t] = amp * sv;
    }
#pragma unroll
    for (int k = 0; k < K_N; ++k) {
        float ar = 0.f, ai = 0.f;
#pragma unroll
        for (int t = 0; t < T_N; ++t) {
            float pr = pri[(k * T_N + t) * 2], pim = pri[(k * T_N + t) * 2 + 1];
            ar += pr * hre[t] - pim * him[t];
            ai += pr * him[t] + pim * hre[t];
        }
        wb[k * 32]        = f2bf(ar * phc - ai * phs);
        wb[(22 + k) * 32] = f2bf(ar * phs + ai * phc);
    }
#pragma unroll
    for (int r = 0; r < R_N; ++r) {
        float dx = rxs[r * 3 + 0] - px, dy = rxs[r * 3 + 1] - py, dz = rxs[r * 3 + 2] - pz;
        float d = sqrtf(dx * dx + dy * dy + dz * dz);
        float amp = 1e-3f / (d * d);
        float sv, cv; fast_sincos(coef * d, &sv, &cv);
        float cr = amp * cv, ci = amp * sv;
        wb[(6 + r) * 32]  = f2bf(cr * phc - ci * phs);
        wb[(28 + r) * 32] = f2bf(cr * phs + ci * phc);
    }
#pragma unroll
    for (int row = 44; row < 48; ++row) wb[row * 32] = 0;
}

// ========== GEMM: [48 x KP] x [KP x 800] bf16 per f, B generated in LDS =======
// 1000 blocks (5f x 25nblk x 8ksp) x 128 thr (2 waves). Split-K partials are
// merged with atomicAdd into the single Cp plane (stage pre-zeroes it).
// Col pairing: n = 2s -> Re(H2[m][s]), n = 2s+1 -> Im(H2[m][s]) — each (m,s)
// sincos computed exactly once. Sincos stays OUT of the MFMA dep chain
// (cooperative produce into double-buffered LDS; round-17 lesson).
__global__ __launch_bounds__(128) void gemm_fused_kernel(
    const ushort* __restrict__ Wbf, const float* __restrict__ fin,
    const float* __restrict__ metap, const float* __restrict__ scenep,
    float* __restrict__ Cp)
{
    const int wk = blockIdx.x;
    const int f = wk / 200;
    const int rem = wk % 200;
    const int nblk = rem / SPK;
    const int ksp = rem % SPK;
    const int t128 = threadIdx.x;
    const int wave = t128 >> 6;
    const int lane = t128 & 63;
    const int quad = lane >> 4;
    const int l16 = lane & 15;
    const int kbeg = ksp * KCNT;

    __shared__ ushort tile[2][32][40];

    // producer role: thread (p, kq) computes k = kq*4..+3 for scene slot p
    const int p  = t128 & 15;
    const int kq = t128 >> 4;                    // 0..7
    const int s  = nblk * 16 + p;                // < 400
    const float coef = NEG_TWO_PI_OVER_C * fin[f];
    const float sx = scenep[s * 3 + 0];
    const float sy = scenep[s * 3 + 1];
    const float sz = scenep[s * 3 + 2];

    const int n = nblk * 32 + wave * 16 + l16;   // < 800, col = 2s(+1)

    f32x4 acc0 = {0.f, 0.f, 0.f, 0.f};
    f32x4 acc1 = {0.f, 0.f, 0.f, 0.f};
    f32x4 acc2 = {0.f, 0.f, 0.f, 0.f};

    auto produce = [&](int buf, int kb) {
        const int k0 = kq * 4;
        const int mb = kb * 32 + k0;
        s16x4 r4, i4;
#pragma unroll
        for (int j = 0; j < 4; ++j) {
            const int m = mb + j;
            float re = 0.f, im = 0.f;
            if (m < M_N) {
                float px = metap[m * 3 + 0], py = metap[m * 3 + 1], pz = metap[m * 3 + 2];
                float dx = px - sx, dy = py - sy, dz = pz - sz;
                float d = sqrtf(dx * dx + dy * dy + dz * dz);
                float amp = 1e-3f / (d * d);
                float sv, cv; fast_sincos(coef * d, &sv, &cv);
                re = amp * cv; im = amp * sv;
            }
            r4[j] = (short)f2bf(re);
            i4[j] = (short)f2bf(im);
        }
        *(s16x4*)&tile[buf][2 * p][k0]     = r4;   // Re -> col 2s
        *(s16x4*)&tile[buf][2 * p + 1][k0] = i4;   // Im -> col 2s+1
    };

    produce(0, kbeg);
    __syncthreads();

    for (int kk = 0; kk < KCNT; ++kk) {
        const int kb = kbeg + kk;
        const int cur = kk & 1;
        if (kk + 1 < KCNT) produce(cur ^ 1, kb + 1);   // parallel sincos, other buf

        bf16x8 b = *(const bf16x8*)&tile[cur][wave * 16 + l16][quad * 8];
        const ushort* wbase = Wbf + ((size_t)(f * NK + kb) * 48) * 32 + quad * 8;
        bf16x8 a0 = *(const bf16x8*)(wbase + (size_t)l16 * 32);
        bf16x8 a1 = *(const bf16x8*)(wbase + (size_t)(16 + l16) * 32);
        bf16x8 a2 = *(const bf16x8*)(wbase + (size_t)(32 + l16) * 32);
        acc0 = __builtin_amdgcn_mfma_f32_16x16x32_bf16(a0, b, acc0, 0, 0, 0);
        acc1 = __builtin_amdgcn_mfma_f32_16x16x32_bf16(a1, b, acc1, 0, 0, 0);
        acc2 = __builtin_amdgcn_mfma_f32_16x16x32_bf16(a2, b, acc2, 0, 0, 0);
        __syncthreads();
    }

    // C/D layout: col = lane&15, row = quad*4 + reg. Atomic merge of split-K.
    float* cb = Cp + (size_t)f * 48 * 800;
#pragma unroll
    for (int i = 0; i < 4; ++i) {
        int row = quad * 4 + i;
        atomicAdd(&cb[(size_t)row * 800 + n],        acc0[i]);
        atomicAdd(&cb[(size_t)(16 + row) * 800 + n], acc1[i]);
        atomicAdd(&cb[(size_t)(32 + row) * 800 + n], acc2[i]);
    }
}

// Complex reassembly from merged plane (col 2s = Re, 2s+1 = Im). 4 loads.
__device__ __forceinline__ void combineC(const float* __restrict__ Cp, int f, int row,
                                         int s, float* re, float* im) {
    const float* c = Cp + (size_t)f * 48 * 800;
    float arr = c[(size_t)row * 800 + 2 * s];            // ReA*ReB
    float ari = c[(size_t)row * 800 + 2 * s + 1];        // ReA*ImB
    float air = c[(size_t)(22 + row) * 800 + 2 * s];     // ImA*ReB
    float aii = c[(size_t)(22 + row) * 800 + 2 * s + 1]; // ImA*ImB
    *re = arr - aii;
    *im = ari + air;
}

// =================== epilogue (750 SA works + 480 mic works) ==================
__global__ __launch_bounds__(256) void epilogue2_kernel(
    const float* __restrict__ Cp, const float* __restrict__ T,
    float* __restrict__ out)
{
    __shared__ float cre[S_N], cim[S_N];
    __shared__ float pR[256], pI[256];
    const int tid = threadIdx.x;
    const int blk = blockIdx.x;

    if (blk < SA_WORKS) {
        int i = blk * 256 + tid;           // 750*256 == 192000
        int s = i % S_N; int rest = i / S_N;
        int k = rest % K_N; rest /= K_N;
        int f = rest % F_N; int r = rest / F_N;

        float ar, ai, br, bi;
        combineC(Cp, f, k, s, &ar, &ai);
        combineC(Cp, f, 6 + r, s, &br, &bi);
        float cr = ar * br - ai * bi;
        float ci = ar * bi + ai * br;

        int base = (r * F_N + f) * 72;
#pragma unroll
        for (int j = 0; j < 12; ++j) {
            int row = base + j * K_N + k;
            out[SA_BASE + (size_t)row * S_N + s] = cr;
            out[SA_BASE + (size_t)(5760 + row) * S_N + s] = ci;
        }
    } else {
        int bk = blk - SA_WORKS;           // 0..479
        int k = bk % K_N;
        int f = (bk / K_N) % F_N;
        int r = bk / (K_N * F_N);

        for (int s = tid; s < S_N; s += 256) {
            float ar, ai, br, bi;
            combineC(Cp, f, k, s, &ar, &ai);
            combineC(Cp, f, 6 + r, s, &br, &bi);
            cre[s] = ar * br - ai * bi;
            cim[s] = ar * bi + ai * br;
        }
        __syncthreads();

        const int b = tid & 127;
        const int hs = tid >> 7;
        float accR = 0.f, accI = 0.f;
        const int sBeg = hs * 200, sEnd = sBeg + 200;
#pragma unroll 4
        for (int s = sBeg; s < sEnd; ++s) {
            float tv = T[s * B_N + b];
            accR += cre[s] * tv;
            accI += cim[s] * tv;
        }
        pR[tid] = accR; pI[tid] = accI;
        __syncthreads();
        if (tid < 128) {
            accR = pR[tid] + pR[tid + 128];
            accI = pI[tid] + pI[tid + 128];
            int base = (r * F_N + f) * 72;
#pragma unroll
            for (int j = 0; j < 12; ++j) {
                int row = base + j * K_N + k;
                out[MIC_BASE + (size_t)row * B_N + b] = accR;
                out[MIC_BASE + (size_t)(5760 + row) * B_N + b] = accI;
            }
        }
    }
}

// ---------------- Fallback path (round-14, used if ws too small) ----------------
#define SA_BLOCKS 750
__global__ __launch_bounds__(256) void prep_kernel(
    const float* __restrict__ w, const float* __restrict__ meta_theta,
    const float* __restrict__ fin, const float* __restrict__ txp,
    const float* __restrict__ rxp, const float* __restrict__ metap,
    float* __restrict__ A1, float* __restrict__ H4p)
{
    __shared__ float pri[K_N * T_N * 2];
    __shared__ float txs[T_N * 3];
    __shared__ float rxs[R_N * 3];
    const int tid = threadIdx.x;
    const int f = blockIdx.x / 15;
    const int mblk = blockIdx.x % 15;

    if (tid < K_N * T_N) {
        float sv, cv; fast_sincos(w[f * (K_N * T_N) + tid], &sv, &cv);
        pri[tid * 2] = cv; pri[tid * 2 + 1] = sv;
    }
    if (tid >= 64 && tid < 64 + T_N * 3) txs[tid - 64] = txp[tid - 64];
    if (tid >= 128 && tid < 128 + R_N * 3) rxs[tid - 128] = rxp[tid - 128];
    __syncthreads();

    const int m = mblk * 256 + tid;
    if (m >= M_N) return;

    const float px = metap[m * 3 + 0];
    const float py = metap[m * 3 + 1];
    const float pz = metap[m * 3 + 2];
    const float coef = NEG_TWO_PI_OVER_C * fin[f];

    float th = meta_theta[m];
    th = fminf(fmaxf(th, -PI_F), CLIP_HI);
    float phs, phc; fast_sincos(th, &phs, &phc);

    float hre[T_N], him[T_N];
#pragma unroll
    for (int t = 0; t < T_N; ++t) {
        float dx = txs[t * 3 + 0] - px, dy = txs[t * 3 + 1] - py, dz = txs[t * 3 + 2] - pz;
        float d = sqrtf(dx * dx + dy * dy + dz * dz);
        float amp = 1e-3f / (d * d);
        float sv, cv; fast_sincos(coef * d, &sv, &cv);
        hre[t] = amp * cv; him[t] = amp * sv;
    }
    float* a1 = A1 + ((size_t)f * M_N + m) * (K_N * 2);
#pragma unroll
    for (int k = 0; k < K_N; ++k) {
        float ar = 0.f, ai = 0.f;
#pragma unroll
        for (int t = 0; t < T_N; ++t) {
            float pr = pri[(k * T_N + t) * 2], pim = pri[(k * T_N + t) * 2 + 1];
            ar += pr * hre[t] - pim * him[t];
            ai += pr * him[t] + pim * hre[t];
        }
        a1[k * 2]     = ar * phc - ai * phs;
        a1[k * 2 + 1] = ar * phs + ai * phc;
    }
    float* h4 = H4p + ((size_t)f * M_N + m) * (R_N * 2);
#pragma unroll
    for (int r = 0; r < R_N; ++r) {
        float dx = rxs[r * 3 + 0] - px, dy = rxs[r * 3 + 1] - py, dz = rxs[r * 3 + 2] - pz;
        float d = sqrtf(dx * dx + dy * dy + dz * dz);
        float amp = 1e-3f / (d * d);
        float sv, cv; fast_sincos(coef * d, &sv, &cv);
        float cr = amp * cv, ci = amp * sv;
        h4[r * 2]     = cr * phc - ci * phs;
        h4[r * 2 + 1] = cr * phs + ci * phc;
    }
}

__global__ __launch_bounds__(256, 2) void main_kernel(
    const float* __restrict__ fin, const float* __restrict__ metap,
    const float* __restrict__ scenep, const float* __restrict__ A1,
    const float* __restrict__ H4p, float* __restrict__ A2, float* __restrict__ Bm)
{
    const int f = blockIdx.x / 200;
    const int sq = blockIdx.x % 200;
    const int s0 = 2 * sq, s1 = s0 + 1;
    const int tid = threadIdx.x;

    const float coef = NEG_TWO_PI_OVER_C * fin[f];
    const float sx0 = scenep[s0 * 3], sy0 = scenep[s0 * 3 + 1], sz0 = scenep[s0 * 3 + 2];
    const float sx1 = scenep[s1 * 3], sy1 = scenep[s1 * 3 + 1], sz1 = scenep[s1 * 3 + 2];

    float acc[88];
#pragma unroll
    for (int i = 0; i < 88; ++i) acc[i] = 0.f;

    const float4* a1base = (const float4*)(A1 + (size_t)f * M_N * (K_N * 2));
    const float4* h4base = (const float4*)(H4p + (size_t)f * M_N * (R_N * 2));

    for (int m = tid; m < M_N; m += 256) {
        float px = metap[m * 3 + 0], py = metap[m * 3 + 1], pz = metap[m * 3 + 2];
        float dx0 = px - sx0, dy0 = py - sy0, dz0 = pz - sz0;
        float d0 = sqrtf(dx0 * dx0 + dy0 * dy0 + dz0 * dz0);
        float dx1 = px - sx1, dy1 = py - sy1, dz1 = pz - sz1;
        float d1 = sqrtf(dx1 * dx1 + dy1 * dy1 + dz1 * dz1);
        float sv0, cv0, sv1, cv1;
        fast_sincos(coef * d0, &sv0, &cv0);
        fast_sincos(coef * d1, &sv1, &cv1);
        float amp0 = 1e-3f / (d0 * d0), amp1 = 1e-3f / (d1 * d1);
        float h2r0 = amp0 * cv0, h2i0 = amp0 * sv0;
        float h2r1 = amp1 * cv1, h2i1 = amp1 * sv1;

        const float4* a1 = a1base + (size_t)m * 3;
#pragma unroll
        for (int q = 0; q < 3; ++q) {
            float4 v = a1[q];
            acc[4 * q + 0] += v.x * h2r0 - v.y * h2i0;
            acc[4 * q + 1] += v.x * h2i0 + v.y * h2r0;
            acc[4 * q + 2] += v.z * h2r0 - v.w * h2i0;
            acc[4 * q + 3] += v.z * h2i0 + v.w * h2r0;
            acc[44 + 4 * q + 0] += v.x * h2r1 - v.y * h2i1;
            acc[44 + 4 * q + 1] += v.x * h2i1 + v.y * h2r1;
            acc[44 + 4 * q + 2] += v.z * h2r1 - v.w * h2i1;
            acc[44 + 4 * q + 3] += v.z * h2i1 + v.w * h2r1;
        }
        const float4* h4 = h4base + (size_t)m * 8;
#pragma unroll
        for (int q = 0; q < 8; ++q) {
            float4 v = h4[q];
            acc[12 + 4 * q + 0] += v.x * h2r0 - v.y * h2i0;
            acc[12 + 4 * q + 1] += v.x * h2i0 + v.y * h2r0;
            acc[12 + 4 * q + 2] += v.z * h2r0 - v.w * h2i0;
            acc[12 + 4 * q + 3] += v.z * h2i0 + v.w * h2r0;
            acc[56 + 4 * q + 0] += v.x * h2r1 - v.y * h2i1;
            acc[56 + 4 * q + 1] += v.x * h2i1 + v.y * h2r1;
            acc[56 + 4 * q + 2] += v.z * h2r1 - v.w * h2i1;
            acc[56 + 4 * q + 3] += v.z * h2i1 + v.w * h2r1;
        }
    }

#pragma unroll
    for (int off = 32; off > 0; off >>= 1) {
#pragma unroll
        for (int i = 0; i < 88; ++i) acc[i] += __shfl_down(acc[i], off);
    }
    __shared__ float red[4][88];
    const int wave = tid >> 6, lane = tid & 63;
    if (lane == 0) {
#pragma unroll
        for (int i = 0; i < 88; ++i) red[wave][i] = acc[i];
    }
    __syncthreads();
    if (tid < 88) {
        float v = red[0][tid] + red[1][tid] + red[2][tid] + red[3][tid];
        int half = tid / 44, slot = tid - 44 * half;
        int s = half ? s1 : s0;
        if (slot < 12) {
            int k = slot >> 1, c = slot & 1;
            A2[(((size_t)f * K_N + k) * S_N + s) * 2 + c] = v;
        } else {
            int j = slot - 12; int r = j >> 1, c = j & 1;
            Bm[(((size_t)f * S_N + s) * R_N + r) * 2 + c] = v;
        }
    }
}

__global__ __launch_bounds__(256) void epilogue_kernel(
    const float* __restrict__ A2, const float* __restrict__ Bm,
    const float* __restrict__ T, float* __restrict__ out)
{
    __shared__ float cre[S_N], cim[S_N];
    __shared__ float pR[256], pI[256];
    const int tid = threadIdx.x;
    const int blk = blockIdx.x;

    if (blk < SA_BLOCKS) {
        int i = blk * 256 + tid;
        int s = i % S_N; int rest = i / S_N;
        int k = rest % K_N; rest /= K_N;
        int f = rest % F_N; int r = rest / F_N;

        float ar = A2[((f * K_N + k) * S_N + s) * 2];
        float ai = A2[((f * K_N + k) * S_N + s) * 2 + 1];
        float br = Bm[((f * S_N + s) * R_N + r) * 2];
        float bi = Bm[((f * S_N + s) * R_N + r) * 2 + 1];
        float cr = ar * br - ai * bi;
        float ci = ar * bi + ai * br;

        int base = (r * F_N + f) * 72;
#pragma unroll
        for (int j = 0; j < 12; ++j) {
            int row = base + j * K_N + k;
            out[SA_BASE + (size_t)row * S_N + s] = cr;
            out[SA_BASE + (size_t)(5760 + row) * S_N + s] = ci;
        }
    } else {
        int bk = blk - SA_BLOCKS;
        int k = bk % K_N;
        int f = (bk / K_N) % F_N;
        int r = bk / (K_N * F_N);

        for (int s = tid; s < S_N; s += 256) {
            float ar = A2[((f * K_N + k) * S_N + s) * 2];
            float ai = A2[((f * K_N + k) * S_N + s) * 2 + 1];
            float br = Bm[((f * S_N + s) * R_N + r) * 2];
            float bi = Bm[((f * S_N + s) * R_N + r) * 2 + 1];
            cre[s] = ar * br - ai * bi;
            cim[s] = ar * bi + ai * br;
        }
        __syncthreads();

        const int b = tid & 127;
        const int hs = tid >> 7;
        float accR = 0.f, accI = 0.f;
        const int sBeg = hs * 200, sEnd = sBeg + 200;
#pragma unroll 4
        for (int s = sBeg; s < sEnd; ++s) {
            float tv = T[s * B_N + b];
            accR += cre[s] * tv;
            accI += cim[s] * tv;
        }
        pR[tid] = accR; pI[tid] = accI;
        __syncthreads();
        if (tid < 128) {
            accR = pR[tid] + pR[tid + 128];
            accI = pI[tid] + pI[tid + 128];
            int base = (r * F_N + f) * 72;
#pragma unroll
            for (int j = 0; j < 12; ++j) {
                int row = base + j * K_N + k;
                out[MIC_BASE + (size_t)row * B_N + b] = accR;
                out[MIC_BASE + (size_t)(5760 + row) * B_N + b] = accI;
            }
        }
    }
}

extern "C" void kernel_launch(void* const* d_in, const int* in_sizes, int n_in,
                              void* d_out, int out_size, void* d_ws, size_t ws_size,
                              hipStream_t stream) {
    const float* T  = (const float*)d_in[0];
    const float* w  = (const float*)d_in[1];
    const float* th = (const float*)d_in[2];
    const float* fr = (const float*)d_in[3];
    const float* tx = (const float*)d_in[4];
    const float* rx = (const float*)d_in[5];
    const float* mp = (const float*)d_in[6];
    const float* sp = (const float*)d_in[7];

    float* out = (float*)d_out;

    if (ws_size >= WS_NEED) {
        ushort* Wbf = (ushort*)d_ws;
        float* Cp = (float*)((char*)d_ws + (size_t)W_ELEMS * 2);

        stage_kernel<<<STAGE_BLOCKS, 256, 0, stream>>>(w, th, fr, tx, rx, mp, Wbf, Cp);
        gemm_fused_kernel<<<1000, 128, 0, stream>>>(Wbf, fr, mp, sp, Cp);
        epilogue2_kernel<<<EPI_WORKS, 256, 0, stream>>>(Cp, T, out);
    } else {
        float* ws  = (float*)d_ws;
        float* A1  = ws;
        float* H4p = ws + 216000;
        float* A2  = ws + 792000;
        float* Bm  = ws + 816000;

        prep_kernel<<<75, 256, 0, stream>>>(w, th, fr, tx, rx, mp, A1, H4p);
        main_kernel<<<F_N * 200, 256, 0, stream>>>(fr, mp, sp, A1, H4p, A2, Bm);
        epilogue_kernel<<<SA_BLOCKS + 480, 256, 0, stream>>>(A2, Bm, T, out);
    }
}